// Round 10
// baseline (468.155 us; speedup 1.0000x reference)
//
#include <hip/hip_runtime.h>
#include <hip/hip_bf16.h>
#include <hip/hip_cooperative_groups.h>

namespace cg = cooperative_groups;

// ---------------- types & helpers ----------------
typedef __attribute__((ext_vector_type(4))) float  f32x4;
typedef __attribute__((ext_vector_type(8))) __bf16 bf16x8;

typedef __attribute__((address_space(1))) void gvoid_t;
typedef __attribute__((address_space(3))) void lvoid_t;

__device__ __forceinline__ void gld16(const void* g, void* l) {
    __builtin_amdgcn_global_load_lds((const gvoid_t*)g, (lvoid_t*)l, 16, 0, 0);
}

template <int N> __device__ __forceinline__ void vwait() {
    if constexpr (N == 0)      asm volatile("s_waitcnt vmcnt(0)" ::: "memory");
    else if constexpr (N == 6) asm volatile("s_waitcnt vmcnt(6)" ::: "memory");
    else if constexpr (N == 8) asm volatile("s_waitcnt vmcnt(8)" ::: "memory");
}

__device__ __forceinline__ unsigned short f2bf(float f) {
    unsigned u = __builtin_bit_cast(unsigned, f);
    u += 0x7fffu + ((u >> 16) & 1u);
    return (unsigned short)(u >> 16);
}
__device__ __forceinline__ float bf2f(unsigned short u) {
    return __builtin_bit_cast(float, (unsigned)u << 16);
}
__device__ __forceinline__ float silu(float x) {
    return x / (1.f + __expf(-x));
}

// log-depth powers: dA[n] = p^(n+1), n=0..15 (depth ~5)
__device__ __forceinline__ void powers16(float p, float* dA) {
    float p2 = p * p, p4 = p2 * p2, p8 = p4 * p4, p16 = p8 * p8;
    float q[5] = {p, p2, p4, p8, p16};
    #pragma unroll
    for (int n = 0; n < 16; ++n) {
        int m = n + 1;
        float r = 1.f;
        bool first = true;
        #pragma unroll
        for (int bit = 0; bit < 5; ++bit) {
            if (m & (1 << bit)) {
                r = first ? q[bit] : r * q[bit];
                first = false;
            }
        }
        dA[n] = r;
    }
}

// ---------------- fused prep: LayerNorm + 4 weight transposes ----------------
__device__ __forceinline__ void tr_cvt(const float* __restrict__ in,
                                       unsigned short* __restrict__ out,
                                       int K, int N, int Npad, int bnb, int bkb,
                                       float* sh) {
    float (*t)[33] = (float(*)[33])sh;
    int bn = bnb * 32, bk = bkb * 32;
    int c = threadIdx.x & 31, r0 = threadIdx.x >> 5;
    #pragma unroll
    for (int rr = r0; rr < 32; rr += 8) {
        int k = bk + rr, n = bn + c;
        t[rr][c] = (k < K && n < N) ? in[(size_t)k * N + n] : 0.f;
    }
    __syncthreads();
    #pragma unroll
    for (int rr = r0; rr < 32; rr += 8) {
        int n = bn + rr, k = bk + c;
        if (n < Npad && k < K) out[(size_t)n * K + k] = f2bf(t[c][rr]);
    }
}

__global__ __launch_bounds__(256) void k_prep(const float* __restrict__ x,
                                              const float* __restrict__ g,
                                              const float* __restrict__ b,
                                              unsigned short* __restrict__ xn,
                                              const float* __restrict__ W_in,  unsigned short* __restrict__ WIN_T,
                                              const float* __restrict__ W_out, unsigned short* __restrict__ WOUT_T,
                                              const float* __restrict__ W_dt,  unsigned short* __restrict__ WDT_T,
                                              const float* __restrict__ W_x,   unsigned short* __restrict__ WX_T) {
    __shared__ float sh[32 * 33];
    int bid = blockIdx.x;
    if (bid < 2048) {
        int row = bid;
        const float4* xr = (const float4*)(x + (size_t)row * 1024);
        float4 v = xr[threadIdx.x];
        float s  = v.x + v.y + v.z + v.w;
        float ss = v.x*v.x + v.y*v.y + v.z*v.z + v.w*v.w;
        #pragma unroll
        for (int o = 32; o > 0; o >>= 1) { s += __shfl_down(s, o); ss += __shfl_down(ss, o); }
        if ((threadIdx.x & 63) == 0) { sh[threadIdx.x >> 6] = s; sh[4 + (threadIdx.x >> 6)] = ss; }
        __syncthreads();
        s  = sh[0] + sh[1] + sh[2] + sh[3];
        ss = sh[4] + sh[5] + sh[6] + sh[7];
        float mu  = s * (1.f / 1024.f);
        float inv = rsqrtf(ss * (1.f / 1024.f) - mu * mu + 1e-5f);
        float4 gv = ((const float4*)g)[threadIdx.x];
        float4 bv = ((const float4*)b)[threadIdx.x];
        ushort4 o4;
        o4.x = f2bf((v.x - mu) * inv * gv.x + bv.x);
        o4.y = f2bf((v.y - mu) * inv * gv.y + bv.y);
        o4.z = f2bf((v.z - mu) * inv * gv.z + bv.z);
        o4.w = f2bf((v.w - mu) * inv * gv.w + bv.w);
        ((ushort4*)xn)[(size_t)row * 256 + threadIdx.x] = o4;
    } else if (bid < 6144) {
        int i = bid - 2048;  tr_cvt(W_in,  WIN_T,  1024, 4096, 4096, i & 127, i >> 7, sh);
    } else if (bid < 8192) {
        int i = bid - 6144;  tr_cvt(W_out, WOUT_T, 2048, 1024, 1024, i & 31,  i >> 5, sh);
    } else if (bid < 8320) {
        int i = bid - 8192;  tr_cvt(W_dt,  WDT_T,  64,   2048, 2048, i & 63,  i >> 6, sh);
    } else {
        int i = bid - 8320;  tr_cvt(W_x,   WX_T,   2048, 96,   128,  i & 3,   i >> 2, sh);
    }
}

// ---------------- pipelined bf16 MFMA GEMM (2-phase, BK=64, XOR-swizzled LDS) ----
// EPI: 0 = fp32 -> C; 1 = softplus(x+bias[col]) -> C;
//      2 = col<2048 ? bf16 -> C2 : bf16(silu) -> C3   (both ld 2048)
template <int BM, int BN, int EPI>
__global__ __launch_bounds__(256) void k_gemm2(const unsigned short* __restrict__ A,
                                               const unsigned short* __restrict__ Bt,
                                               float* __restrict__ C,
                                               unsigned short* __restrict__ C2,
                                               unsigned short* __restrict__ C3,
                                               int kchunk, int lda, int ldb, int ldc,
                                               size_t zstride,
                                               const float* __restrict__ bias) {
    constexpr int PA = BM / 32, PB = BN / 32, NV = PA + PB;
    constexpr int MF = BM / 32, NF = BN / 32;
    __shared__ __attribute__((aligned(16))) unsigned short smA[2 * BM * 64];
    __shared__ __attribute__((aligned(16))) unsigned short smB[2 * BN * 64];

    int tid = threadIdx.x, wave = tid >> 6, lane = tid & 63;
    int bm = blockIdx.x * BM, bn = blockIdx.y * BN;
    int kstart = blockIdx.z * kchunk;
    int nt = kchunk >> 6;
    C += (size_t)blockIdx.z * zstride;
    int wm = (wave >> 1) * (BM / 2), wn = (wave & 1) * (BN / 2);
    int lr = lane & 15, lq = lane >> 4;
    int srow = wave * 8 + (lane >> 3);
    int scg  = lane & 7;

    f32x4 acc[MF][NF] = {};

    auto STAGE = [&](int buf, int k0) {
        unsigned short* dA = smA + buf * (BM * 64) + wave * 512;
        unsigned short* dB = smB + buf * (BN * 64) + wave * 512;
        #pragma unroll
        for (int p = 0; p < PA; ++p) {
            int row = p * 32 + srow;
            int gcol = ((scg ^ (row & 7)) << 3) + k0;
            gld16(A + (size_t)(bm + row) * lda + gcol, dA + p * 2048);
        }
        #pragma unroll
        for (int p = 0; p < PB; ++p) {
            int row = p * 32 + srow;
            int gcol = ((scg ^ (row & 7)) << 3) + k0;
            gld16(Bt + (size_t)(bn + row) * ldb + gcol, dB + p * 2048);
        }
    };

    STAGE(0, kstart);
    for (int t = 0; t < nt; ++t) {
        int cur = t & 1;
        if (t + 1 < nt) { STAGE(cur ^ 1, kstart + (t + 1) * 64); vwait<NV>(); }
        else            { vwait<0>(); }
        __builtin_amdgcn_s_barrier();
        const unsigned short* sA = smA + cur * (BM * 64);
        const unsigned short* sB = smB + cur * (BN * 64);
        #pragma unroll
        for (int ks = 0; ks < 2; ++ks) {
            int cg = (ks * 4 + lq) ^ (lr & 7);
            bf16x8 af[MF], bfv[NF];
            #pragma unroll
            for (int i = 0; i < MF; ++i)
                af[i] = *(const bf16x8*)(sA + (wm + i * 16 + lr) * 64 + (cg << 3));
            #pragma unroll
            for (int i = 0; i < NF; ++i)
                bfv[i] = *(const bf16x8*)(sB + (wn + i * 16 + lr) * 64 + (cg << 3));
            #pragma unroll
            for (int mi = 0; mi < MF; ++mi)
                #pragma unroll
                for (int ni = 0; ni < NF; ++ni)
                    acc[mi][ni] = __builtin_amdgcn_mfma_f32_16x16x32_bf16(af[mi], bfv[ni], acc[mi][ni], 0, 0, 0);
        }
        __builtin_amdgcn_s_barrier();
    }

    #pragma unroll
    for (int mi = 0; mi < MF; ++mi) {
        #pragma unroll
        for (int ni = 0; ni < NF; ++ni) {
            int c = bn + wn + ni * 16 + lr;
            #pragma unroll
            for (int v = 0; v < 4; ++v) {
                int r = bm + wm + mi * 16 + (lq << 2) + v;
                float val = acc[mi][ni][v];
                if (EPI == 0) {
                    C[(size_t)r * ldc + c] = val;
                } else if (EPI == 1) {
                    val += bias[c];
                    val = (val > 20.f) ? val : log1pf(__expf(val));
                    C[(size_t)r * ldc + c] = val;
                } else {
                    if (c < 2048) C2[(size_t)r * 2048 + c] = f2bf(val);
                    else          C3[(size_t)r * 2048 + (c - 2048)] = f2bf(silu(val));
                }
            }
        }
    }
}

// ---------------- split-K reduce (8 partials) + dtr bf16 ----------------
__global__ __launch_bounds__(256) void k_red8(const float* __restrict__ part,
                                              float* __restrict__ dbl,
                                              unsigned short* __restrict__ dtr) {
    int idx = blockIdx.x * 256 + threadIdx.x;   // 2048*128
    float s = 0.f;
    #pragma unroll
    for (int z = 0; z < 8; ++z) s += part[(size_t)z * 262144 + idx];
    dbl[idx] = s;
    int r = idx >> 7, c = idx & 127;
    if (c < 64) dtr[r * 64 + c] = f2bf(s);
}

// ---------------- causal depthwise conv (width 4, bf16 in) + SiLU -> bf16 ------
__global__ __launch_bounds__(256) void k_conv2(const unsigned short* __restrict__ UB,
                                               const float* __restrict__ cw,
                                               const float* __restrict__ cb,
                                               unsigned short* __restrict__ ucb) {
    int idx = blockIdx.x * 256 + threadIdx.x;   // (b*L+l)*2048 + e
    int e  = idx & 2047;
    int bl = idx >> 11;
    int l  = bl & 1023;
    float acc = cb[e];
    float4 wv = *(const float4*)(cw + e * 4);
    float w4[4] = {wv.x, wv.y, wv.z, wv.w};
    #pragma unroll
    for (int k = 0; k < 4; ++k) {
        int ls = l - 3 + k;
        if (ls >= 0) acc += w4[k] * bf2f(UB[(size_t)(bl - 3 + k) * 2048 + e]);
    }
    ucb[idx] = f2bf(silu(acc));
}

// ================= fused cooperative scan (p1+p2+p3, 2 grid syncs) =============
// 512 blocks x 256 threads; block (b,eblk,c) owns chunk c of 32 steps for 256 e's.
// Phase1 caches dt/uc in LDS; phase3 replays from LDS (no DT/UCB re-read).
__global__ __launch_bounds__(256) void k_scan_fused(const unsigned short* __restrict__ ucb,
                                                    const float* __restrict__ dt,
                                                    const float* __restrict__ dbl,
                                                    const unsigned short* __restrict__ sz,
                                                    const float* __restrict__ A_log,
                                                    const float* __restrict__ D_skip,
                                                    float* __restrict__ aggH,
                                                    float* __restrict__ sdtb,
                                                    float* __restrict__ hinit,
                                                    unsigned short* __restrict__ yg) {
    cg::grid_group grid = cg::this_grid();
    __shared__ float          sd[32][256];   // dt cache (32 KB)
    __shared__ unsigned short su[32][256];   // uc cache (16 KB)
    __shared__ float          sBC[32][32];   // B,C      (4 KB)

    int bid = blockIdx.x;                    // 512 = 2b * 8eblk * 32c
    int c = bid & 31, eblk = (bid >> 5) & 7, b = bid >> 8;
    int t = threadIdx.x;
    int e = eblk * 256 + t;
    int bl0 = b * 1024 + c * 32;
    {
        int r = t >> 3, j = t & 7;
        *(float4*)&sBC[r][j * 4] = *(const float4*)(dbl + (size_t)(bl0 + r) * 128 + 64 + j * 4);
    }
    float Aen[16];
    #pragma unroll
    for (int n = 0; n < 16; ++n) Aen[n] = -__expf(A_log[e * 16 + n]);
    bool fastA = true;
    #pragma unroll
    for (int n = 1; n < 16; ++n)
        fastA = fastA && (fabsf(Aen[n] - (n + 1) * Aen[0]) <= 1e-3f);
    __syncthreads();

    // ---- phase 1: chunk aggregate from h=0, cache dt/uc in LDS ----
    float h[16];
    #pragma unroll
    for (int n = 0; n < 16; ++n) h[n] = 0.f;
    float sdt = 0.f;
    size_t iu = (size_t)bl0 * 2048 + e;
    #pragma unroll 4
    for (int l = 0; l < 32; ++l) {
        float dtv = dt[iu];
        unsigned short uw = ucb[iu];
        sd[l][t] = dtv;
        su[l][t] = uw;
        float dtu = dtv * bf2f(uw);
        float dA[16];
        if (fastA) {
            powers16(__expf(dtv * Aen[0]), dA);
        } else {
            #pragma unroll
            for (int n = 0; n < 16; ++n) dA[n] = __expf(dtv * Aen[n]);
        }
        #pragma unroll
        for (int n = 0; n < 16; ++n)
            h[n] = fmaf(dA[n], h[n], dtu * sBC[l][n]);
        sdt += dtv;
        iu += 2048;
    }
    size_t o = ((size_t)(b * 32 + c) * 16) * 2048 + e;
    #pragma unroll
    for (int n = 0; n < 16; ++n) aggH[o + (size_t)n * 2048] = h[n];
    sdtb[(size_t)(b * 32 + c) * 2048 + e] = sdt;

    grid.sync();

    // ---- phase 2: balanced inter-chunk prefix (first 65536 threads) ----
    int gidx = bid * 256 + t;
    if (gidx < 65536) {
        int b2 = gidx >> 15;
        int n2 = (gidx >> 11) & 15;
        int e2 = gidx & 2047;
        float Aen2 = -__expf(A_log[e2 * 16 + n2]);
        float hh = 0.f;
        #pragma unroll 4
        for (int c2 = 0; c2 < 32; ++c2) {
            size_t base = ((size_t)(b2 * 32 + c2) * 16 + n2) * 2048 + e2;
            hinit[base] = hh;
            float a = __expf(sdtb[(size_t)(b2 * 32 + c2) * 2048 + e2] * Aen2);
            hh = fmaf(a, hh, aggH[base]);
        }
    }

    grid.sync();

    // ---- phase 3: replay chunk from LDS with true initial state ----
    float De = D_skip[e];
    #pragma unroll
    for (int n = 0; n < 16; ++n) h[n] = hinit[o + (size_t)n * 2048];
    iu = (size_t)bl0 * 2048 + e;
    #pragma unroll 4
    for (int l = 0; l < 32; ++l) {
        float dtv = sd[l][t];
        float ucv = bf2f(su[l][t]);
        float szv = bf2f(sz[iu]);
        float dtu = dtv * ucv;
        float dA[16];
        if (fastA) {
            powers16(__expf(dtv * Aen[0]), dA);
        } else {
            #pragma unroll
            for (int n = 0; n < 16; ++n) dA[n] = __expf(dtv * Aen[n]);
        }
        float y0 = 0.f, y1 = 0.f, y2 = 0.f, y3 = 0.f;
        #pragma unroll
        for (int n = 0; n < 16; n += 4) {
            h[n]     = fmaf(dA[n],     h[n],     dtu * sBC[l][n]);
            h[n + 1] = fmaf(dA[n + 1], h[n + 1], dtu * sBC[l][n + 1]);
            h[n + 2] = fmaf(dA[n + 2], h[n + 2], dtu * sBC[l][n + 2]);
            h[n + 3] = fmaf(dA[n + 3], h[n + 3], dtu * sBC[l][n + 3]);
            y0 = fmaf(h[n],     sBC[l][16 + n],     y0);
            y1 = fmaf(h[n + 1], sBC[l][16 + n + 1], y1);
            y2 = fmaf(h[n + 2], sBC[l][16 + n + 2], y2);
            y3 = fmaf(h[n + 3], sBC[l][16 + n + 3], y3);
        }
        float y = (y0 + y1) + (y2 + y3);
        y = (y + ucv * De) * szv;
        yg[iu] = f2bf(y);
        iu += 2048;
    }
}

// ---------------- fallback 3-kernel scan (proven R9 path) ----------------
__global__ __launch_bounds__(256) void k_scan_p1(const unsigned short* __restrict__ ucb,
                                                 const float* __restrict__ dt,
                                                 const float* __restrict__ dbl,
                                                 const float* __restrict__ A_log,
                                                 float* __restrict__ aggH,
                                                 float* __restrict__ sdtb) {
    __shared__ float sB[32][16];
    int bid = blockIdx.x;
    int c = bid & 31, eblk = (bid >> 5) & 7, b = bid >> 8;
    int t = threadIdx.x;
    int e = eblk * 256 + t;
    int bl0 = b * 1024 + c * 32;
    if (t < 128) {
        int r = t >> 2, j4 = t & 3;
        *(float4*)&sB[r][j4 * 4] = *(const float4*)(dbl + (size_t)(bl0 + r) * 128 + 64 + j4 * 4);
    }
    __syncthreads();
    float Aen[16];
    #pragma unroll
    for (int n = 0; n < 16; ++n) Aen[n] = -__expf(A_log[e * 16 + n]);
    bool fastA = true;
    #pragma unroll
    for (int n = 1; n < 16; ++n)
        fastA = fastA && (fabsf(Aen[n] - (n + 1) * Aen[0]) <= 1e-3f);
    float h[16];
    #pragma unroll
    for (int n = 0; n < 16; ++n) h[n] = 0.f;
    float sdt = 0.f;
    size_t iu = (size_t)bl0 * 2048 + e;
    #pragma unroll 4
    for (int l = 0; l < 32; ++l) {
        float dtv = dt[iu];
        float ucv = bf2f(ucb[iu]);
        float dtu = dtv * ucv;
        float dA[16];
        if (fastA) powers16(__expf(dtv * Aen[0]), dA);
        else {
            #pragma unroll
            for (int n = 0; n < 16; ++n) dA[n] = __expf(dtv * Aen[n]);
        }
        #pragma unroll
        for (int n = 0; n < 16; ++n)
            h[n] = fmaf(dA[n], h[n], dtu * sB[l][n]);
        sdt += dtv;
        iu += 2048;
    }
    size_t o = ((size_t)(b * 32 + c) * 16) * 2048 + e;
    #pragma unroll
    for (int n = 0; n < 16; ++n) aggH[o + (size_t)n * 2048] = h[n];
    sdtb[(size_t)(b * 32 + c) * 2048 + e] = sdt;
}

__global__ __launch_bounds__(256) void k_scan_p2(const float* __restrict__ aggH,
                                                 const float* __restrict__ sdtb,
                                                 const float* __restrict__ A_log,
                                                 float* __restrict__ hinit) {
    int idx = blockIdx.x * 256 + threadIdx.x;
    int b = idx >> 15;
    int n = (idx >> 11) & 15;
    int e = idx & 2047;
    float Aen = -__expf(A_log[e * 16 + n]);
    float h = 0.f;
    #pragma unroll 4
    for (int c = 0; c < 32; ++c) {
        size_t base = ((size_t)(b * 32 + c) * 16 + n) * 2048 + e;
        hinit[base] = h;
        float a = __expf(sdtb[(size_t)(b * 32 + c) * 2048 + e] * Aen);
        h = fmaf(a, h, aggH[base]);
    }
}

__global__ __launch_bounds__(256) void k_scan_p3(const unsigned short* __restrict__ ucb,
                                                 const float* __restrict__ dt,
                                                 const float* __restrict__ dbl,
                                                 const unsigned short* __restrict__ sz,
                                                 const float* __restrict__ A_log,
                                                 const float* __restrict__ D_skip,
                                                 const float* __restrict__ hinit,
                                                 unsigned short* __restrict__ yg) {
    __shared__ float sBC[32][32];
    int bid = blockIdx.x;
    int c = bid & 31, eblk = (bid >> 5) & 7, b = bid >> 8;
    int t = threadIdx.x;
    int e = eblk * 256 + t;
    int bl0 = b * 1024 + c * 32;
    {
        int r = t >> 3, j = t & 7;
        *(float4*)&sBC[r][j * 4] = *(const float4*)(dbl + (size_t)(bl0 + r) * 128 + 64 + j * 4);
    }
    __syncthreads();
    float Aen[16];
    #pragma unroll
    for (int n = 0; n < 16; ++n) Aen[n] = -__expf(A_log[e * 16 + n]);
    bool fastA = true;
    #pragma unroll
    for (int n = 1; n < 16; ++n)
        fastA = fastA && (fabsf(Aen[n] - (n + 1) * Aen[0]) <= 1e-3f);
    float De = D_skip[e];
    size_t o = ((size_t)(b * 32 + c) * 16) * 2048 + e;
    float h[16];
    #pragma unroll
    for (int n = 0; n < 16; ++n) h[n] = hinit[o + (size_t)n * 2048];
    size_t iu = (size_t)bl0 * 2048 + e;
    #pragma unroll 4
    for (int l = 0; l < 32; ++l) {
        float dtv = dt[iu];
        float ucv = bf2f(ucb[iu]);
        float szv = bf2f(sz[iu]);
        float dtu = dtv * ucv;
        float dA[16];
        if (fastA) powers16(__expf(dtv * Aen[0]), dA);
        else {
            #pragma unroll
            for (int n = 0; n < 16; ++n) dA[n] = __expf(dtv * Aen[n]);
        }
        float y0 = 0.f, y1 = 0.f, y2 = 0.f, y3 = 0.f;
        #pragma unroll
        for (int n = 0; n < 16; n += 4) {
            h[n]     = fmaf(dA[n],     h[n],     dtu * sBC[l][n]);
            h[n + 1] = fmaf(dA[n + 1], h[n + 1], dtu * sBC[l][n + 1]);
            h[n + 2] = fmaf(dA[n + 2], h[n + 2], dtu * sBC[l][n + 2]);
            h[n + 3] = fmaf(dA[n + 3], h[n + 3], dtu * sBC[l][n + 3]);
            y0 = fmaf(h[n],     sBC[l][16 + n],     y0);
            y1 = fmaf(h[n + 1], sBC[l][16 + n + 1], y1);
            y2 = fmaf(h[n + 2], sBC[l][16 + n + 2], y2);
            y3 = fmaf(h[n + 3], sBC[l][16 + n + 3], y3);
        }
        float y = (y0 + y1) + (y2 + y3);
        y = (y + ucv * De) * szv;
        yg[iu] = f2bf(y);
        iu += 2048;
    }
}

// ---------------- launch ----------------
extern "C" void kernel_launch(void* const* d_in, const int* in_sizes, int n_in,
                              void* d_out, int out_size, void* d_ws, size_t ws_size,
                              hipStream_t stream) {
    const float* x      = (const float*)d_in[0];
    const float* ln_g   = (const float*)d_in[1];
    const float* ln_b   = (const float*)d_in[2];
    const float* W_in   = (const float*)d_in[3];
    const float* conv_w = (const float*)d_in[4];
    const float* conv_b = (const float*)d_in[5];
    const float* W_x    = (const float*)d_in[6];
    const float* W_dt   = (const float*)d_in[7];
    const float* b_dt   = (const float*)d_in[8];
    const float* A_log  = (const float*)d_in[9];
    const float* D_skip = (const float*)d_in[10];
    const float* W_out  = (const float*)d_in[11];
    float* out = (float*)d_out;

    const size_t needed =
        (size_t)4096 * 1024 * 2 + (size_t)1024 * 2048 * 2 + (size_t)2048 * 64 * 2 +
        (size_t)128 * 2048 * 2 + (size_t)2048 * 1024 * 2 + (size_t)2048 * 4096 * 4 +
        (size_t)2048 * 2048 * 4 + (size_t)2048 * 2048 * 2 + (size_t)2048 * 128 * 4 +
        (size_t)2048 * 64 * 2 + (size_t)2048 * 2048 * 4 + (size_t)2048 * 2048 * 2;
    if (ws_size < needed) return;

    char* w = (char*)d_ws;
    unsigned short* WIN_T  = (unsigned short*)w; w += (size_t)4096 * 1024 * 2;   // 8 MB
    unsigned short* WOUT_T = (unsigned short*)w; w += (size_t)1024 * 2048 * 2;   // 4 MB
    unsigned short* WDT_T  = (unsigned short*)w; w += (size_t)2048 * 64 * 2;
    unsigned short* WX_T   = (unsigned short*)w; w += (size_t)128 * 2048 * 2;
    unsigned short* XN     = (unsigned short*)w; w += (size_t)2048 * 1024 * 2;   // 4 MB
    unsigned short* UB     = (unsigned short*)w; w += (size_t)2048 * 2048 * 2;   // 8 MB
    unsigned short* SZ     = (unsigned short*)w; w += (size_t)2048 * 2048 * 2;   // 8 MB
    unsigned short* UCB    = (unsigned short*)w; w += (size_t)2048 * 2048 * 2;   // 8 MB
    float*          DBL    = (float*)w;          w += (size_t)2048 * 128 * 4;    // 1 MB
    unsigned short* DTR    = (unsigned short*)w; w += (size_t)2048 * 64 * 2;
    float*          DT     = (float*)w;          w += (size_t)2048 * 2048 * 4;   // 16 MB
    unsigned short* YG     = (unsigned short*)w; w += (size_t)2048 * 2048 * 2;   // 8 MB

    // aliases on dead regions:
    // PART (8MB) on WIN_T (dead after GEMM1; PART dead after red8)
    // AGGH (8MB) on WIN_T ; SDT (512KB) on XN ; HINIT (8MB) on UB (dead after conv2)
    float* PART  = (float*)WIN_T;
    float* AGGH  = (float*)WIN_T;
    float* SDT   = (float*)XN;
    float* HINIT = (float*)UB;

    // 1. prep: LN + all weight transposes
    k_prep<<<8576, 256, 0, stream>>>(x, ln_g, ln_b, XN,
                                     W_in, WIN_T, W_out, WOUT_T, W_dt, WDT_T, W_x, WX_T);

    // 2. u,z = xn @ W_in ; u -> UB bf16, z -> SZ = silu(z) bf16
    k_gemm2<128, 128, 2><<<dim3(16, 32, 1), 256, 0, stream>>>(XN, WIN_T, nullptr, UB, SZ, 1024, 1024, 1024, 2048, 0, nullptr);

    // 3. uc(bf16) = silu(conv(u))
    k_conv2<<<16384, 256, 0, stream>>>(UB, conv_w, conv_b, UCB);

    // 4. dbl partials = uc @ W_x (split-K x8)
    k_gemm2<64, 128, 0><<<dim3(32, 1, 8), 256, 0, stream>>>(UCB, WX_T, PART, nullptr, nullptr, 256, 2048, 2048, 128, (size_t)2048 * 128, nullptr);

    // 5. reduce partials -> DBL fp32 + DTR bf16
    k_red8<<<1024, 256, 0, stream>>>(PART, DBL, DTR);

    // 6. dt = softplus(dtr @ W_dt + b_dt)
    k_gemm2<128, 128, 1><<<dim3(16, 16, 1), 256, 0, stream>>>(DTR, WDT_T, DT, nullptr, nullptr, 64, 64, 64, 2048, 0, b_dt);

    // 7. fused cooperative scan (fallback: 3-kernel path)
    {
        const unsigned short* a_ucb = UCB;
        const float* a_dt = DT;
        const float* a_dbl = DBL;
        const unsigned short* a_sz = SZ;
        const float* a_al = A_log;
        const float* a_ds = D_skip;
        float* a_aggH = AGGH;
        float* a_sdt = SDT;
        float* a_hinit = HINIT;
        unsigned short* a_yg = YG;
        void* args[] = {&a_ucb, &a_dt, &a_dbl, &a_sz, &a_al, &a_ds,
                        &a_aggH, &a_sdt, &a_hinit, &a_yg};
        hipError_t err = hipLaunchCooperativeKernel((const void*)k_scan_fused,
                                                    dim3(512), dim3(256),
                                                    args, 0, stream);
        if (err != hipSuccess) {
            k_scan_p1<<<512, 256, 0, stream>>>(UCB, DT, DBL, A_log, AGGH, SDT);
            k_scan_p2<<<256, 256, 0, stream>>>(AGGH, SDT, A_log, HINIT);
            k_scan_p3<<<512, 256, 0, stream>>>(UCB, DT, DBL, SZ, A_log, D_skip, HINIT, YG);
        }
    }

    // 8. out = yg @ W_out
    k_gemm2<64, 128, 0><<<dim3(32, 8, 1), 256, 0, stream>>>(YG, WOUT_T, out, nullptr, nullptr, 2048, 2048, 2048, 1024, 0, nullptr);
}

// Round 11
// 351.809 us; speedup vs baseline: 1.3307x; 1.3307x over previous
//
#include <hip/hip_runtime.h>
#include <hip/hip_bf16.h>

// ---------------- types & helpers ----------------
typedef __attribute__((ext_vector_type(4))) float  f32x4;
typedef __attribute__((ext_vector_type(8))) __bf16 bf16x8;

typedef __attribute__((address_space(1))) void gvoid_t;
typedef __attribute__((address_space(3))) void lvoid_t;

__device__ __forceinline__ void gld16(const void* g, void* l) {
    __builtin_amdgcn_global_load_lds((const gvoid_t*)g, (lvoid_t*)l, 16, 0, 0);
}

template <int N> __device__ __forceinline__ void vwait() {
    if constexpr (N == 0)      asm volatile("s_waitcnt vmcnt(0)" ::: "memory");
    else if constexpr (N == 6) asm volatile("s_waitcnt vmcnt(6)" ::: "memory");
    else if constexpr (N == 8) asm volatile("s_waitcnt vmcnt(8)" ::: "memory");
}

__device__ __forceinline__ unsigned short f2bf(float f) {
    unsigned u = __builtin_bit_cast(unsigned, f);
    u += 0x7fffu + ((u >> 16) & 1u);
    return (unsigned short)(u >> 16);
}
__device__ __forceinline__ float bf2f(unsigned short u) {
    return __builtin_bit_cast(float, (unsigned)u << 16);
}
__device__ __forceinline__ float silu(float x) {
    return x / (1.f + __expf(-x));
}

// log-depth powers: dA[n] = p^(n+1), n=0..15 (depth ~5)
__device__ __forceinline__ void powers16(float p, float* dA) {
    float p2 = p * p, p4 = p2 * p2, p8 = p4 * p4, p16 = p8 * p8;
    float q[5] = {p, p2, p4, p8, p16};
    #pragma unroll
    for (int n = 0; n < 16; ++n) {
        int m = n + 1;
        float r = 1.f;
        bool first = true;
        #pragma unroll
        for (int bit = 0; bit < 5; ++bit) {
            if (m & (1 << bit)) {
                r = first ? q[bit] : r * q[bit];
                first = false;
            }
        }
        dA[n] = r;
    }
}

// ---------------- fused prep: LayerNorm + 4 weight transposes ----------------
__device__ __forceinline__ void tr_cvt(const float* __restrict__ in,
                                       unsigned short* __restrict__ out,
                                       int K, int N, int Npad, int bnb, int bkb,
                                       float* sh) {
    float (*t)[33] = (float(*)[33])sh;
    int bn = bnb * 32, bk = bkb * 32;
    int c = threadIdx.x & 31, r0 = threadIdx.x >> 5;
    #pragma unroll
    for (int rr = r0; rr < 32; rr += 8) {
        int k = bk + rr, n = bn + c;
        t[rr][c] = (k < K && n < N) ? in[(size_t)k * N + n] : 0.f;
    }
    __syncthreads();
    #pragma unroll
    for (int rr = r0; rr < 32; rr += 8) {
        int n = bn + rr, k = bk + c;
        if (n < Npad && k < K) out[(size_t)n * K + k] = f2bf(t[c][rr]);
    }
}

__global__ __launch_bounds__(256) void k_prep(const float* __restrict__ x,
                                              const float* __restrict__ g,
                                              const float* __restrict__ b,
                                              unsigned short* __restrict__ xn,
                                              const float* __restrict__ W_in,  unsigned short* __restrict__ WIN_T,
                                              const float* __restrict__ W_out, unsigned short* __restrict__ WOUT_T,
                                              const float* __restrict__ W_dt,  unsigned short* __restrict__ WDT_T,
                                              const float* __restrict__ W_x,   unsigned short* __restrict__ WX_T) {
    __shared__ float sh[32 * 33];
    int bid = blockIdx.x;
    if (bid < 2048) {
        int row = bid;
        const float4* xr = (const float4*)(x + (size_t)row * 1024);
        float4 v = xr[threadIdx.x];
        float s  = v.x + v.y + v.z + v.w;
        float ss = v.x*v.x + v.y*v.y + v.z*v.z + v.w*v.w;
        #pragma unroll
        for (int o = 32; o > 0; o >>= 1) { s += __shfl_down(s, o); ss += __shfl_down(ss, o); }
        if ((threadIdx.x & 63) == 0) { sh[threadIdx.x >> 6] = s; sh[4 + (threadIdx.x >> 6)] = ss; }
        __syncthreads();
        s  = sh[0] + sh[1] + sh[2] + sh[3];
        ss = sh[4] + sh[5] + sh[6] + sh[7];
        float mu  = s * (1.f / 1024.f);
        float inv = rsqrtf(ss * (1.f / 1024.f) - mu * mu + 1e-5f);
        float4 gv = ((const float4*)g)[threadIdx.x];
        float4 bv = ((const float4*)b)[threadIdx.x];
        ushort4 o4;
        o4.x = f2bf((v.x - mu) * inv * gv.x + bv.x);
        o4.y = f2bf((v.y - mu) * inv * gv.y + bv.y);
        o4.z = f2bf((v.z - mu) * inv * gv.z + bv.z);
        o4.w = f2bf((v.w - mu) * inv * gv.w + bv.w);
        ((ushort4*)xn)[(size_t)row * 256 + threadIdx.x] = o4;
    } else if (bid < 6144) {
        int i = bid - 2048;  tr_cvt(W_in,  WIN_T,  1024, 4096, 4096, i & 127, i >> 7, sh);
    } else if (bid < 8192) {
        int i = bid - 6144;  tr_cvt(W_out, WOUT_T, 2048, 1024, 1024, i & 31,  i >> 5, sh);
    } else if (bid < 8320) {
        int i = bid - 8192;  tr_cvt(W_dt,  WDT_T,  64,   2048, 2048, i & 63,  i >> 6, sh);
    } else {
        int i = bid - 8320;  tr_cvt(W_x,   WX_T,   2048, 96,   128,  i & 3,   i >> 2, sh);
    }
}

// ---------------- pipelined bf16 MFMA GEMM (2-phase, BK=64, XOR-swizzled LDS) ----
// EPI: 0 = fp32 -> C; 1 = softplus(x+bias[col]) -> C (fp32);
//      2 = col<2048 ? bf16 -> C2 : bf16(silu) -> C3   (both ld 2048)
//      3 = softplus(x+bias[col]) -> bf16 -> C2
template <int BM, int BN, int EPI>
__global__ __launch_bounds__(256) void k_gemm2(const unsigned short* __restrict__ A,
                                               const unsigned short* __restrict__ Bt,
                                               float* __restrict__ C,
                                               unsigned short* __restrict__ C2,
                                               unsigned short* __restrict__ C3,
                                               int kchunk, int lda, int ldb, int ldc,
                                               size_t zstride,
                                               const float* __restrict__ bias) {
    constexpr int PA = BM / 32, PB = BN / 32, NV = PA + PB;
    constexpr int MF = BM / 32, NF = BN / 32;
    __shared__ __attribute__((aligned(16))) unsigned short smA[2 * BM * 64];
    __shared__ __attribute__((aligned(16))) unsigned short smB[2 * BN * 64];

    int tid = threadIdx.x, wave = tid >> 6, lane = tid & 63;
    int bm = blockIdx.x * BM, bn = blockIdx.y * BN;
    int kstart = blockIdx.z * kchunk;
    int nt = kchunk >> 6;
    C += (size_t)blockIdx.z * zstride;
    int wm = (wave >> 1) * (BM / 2), wn = (wave & 1) * (BN / 2);
    int lr = lane & 15, lq = lane >> 4;
    int srow = wave * 8 + (lane >> 3);
    int scg  = lane & 7;

    f32x4 acc[MF][NF] = {};

    auto STAGE = [&](int buf, int k0) {
        unsigned short* dA = smA + buf * (BM * 64) + wave * 512;
        unsigned short* dB = smB + buf * (BN * 64) + wave * 512;
        #pragma unroll
        for (int p = 0; p < PA; ++p) {
            int row = p * 32 + srow;
            int gcol = ((scg ^ (row & 7)) << 3) + k0;
            gld16(A + (size_t)(bm + row) * lda + gcol, dA + p * 2048);
        }
        #pragma unroll
        for (int p = 0; p < PB; ++p) {
            int row = p * 32 + srow;
            int gcol = ((scg ^ (row & 7)) << 3) + k0;
            gld16(Bt + (size_t)(bn + row) * ldb + gcol, dB + p * 2048);
        }
    };

    STAGE(0, kstart);
    for (int t = 0; t < nt; ++t) {
        int cur = t & 1;
        if (t + 1 < nt) { STAGE(cur ^ 1, kstart + (t + 1) * 64); vwait<NV>(); }
        else            { vwait<0>(); }
        __builtin_amdgcn_s_barrier();
        const unsigned short* sA = smA + cur * (BM * 64);
        const unsigned short* sB = smB + cur * (BN * 64);
        #pragma unroll
        for (int ks = 0; ks < 2; ++ks) {
            int cg = (ks * 4 + lq) ^ (lr & 7);
            bf16x8 af[MF], bfv[NF];
            #pragma unroll
            for (int i = 0; i < MF; ++i)
                af[i] = *(const bf16x8*)(sA + (wm + i * 16 + lr) * 64 + (cg << 3));
            #pragma unroll
            for (int i = 0; i < NF; ++i)
                bfv[i] = *(const bf16x8*)(sB + (wn + i * 16 + lr) * 64 + (cg << 3));
            #pragma unroll
            for (int mi = 0; mi < MF; ++mi)
                #pragma unroll
                for (int ni = 0; ni < NF; ++ni)
                    acc[mi][ni] = __builtin_amdgcn_mfma_f32_16x16x32_bf16(af[mi], bfv[ni], acc[mi][ni], 0, 0, 0);
        }
        __builtin_amdgcn_s_barrier();
    }

    #pragma unroll
    for (int mi = 0; mi < MF; ++mi) {
        #pragma unroll
        for (int ni = 0; ni < NF; ++ni) {
            int c = bn + wn + ni * 16 + lr;
            #pragma unroll
            for (int v = 0; v < 4; ++v) {
                int r = bm + wm + mi * 16 + (lq << 2) + v;
                float val = acc[mi][ni][v];
                if (EPI == 0) {
                    C[(size_t)r * ldc + c] = val;
                } else if (EPI == 1) {
                    val += bias[c];
                    val = (val > 20.f) ? val : log1pf(__expf(val));
                    C[(size_t)r * ldc + c] = val;
                } else if (EPI == 3) {
                    val += bias[c];
                    val = (val > 20.f) ? val : log1pf(__expf(val));
                    C2[(size_t)r * ldc + c] = f2bf(val);
                } else {
                    if (c < 2048) C2[(size_t)r * 2048 + c] = f2bf(val);
                    else          C3[(size_t)r * 2048 + (c - 2048)] = f2bf(silu(val));
                }
            }
        }
    }
}

// ---------------- split-K reduce (8 partials) + dtr bf16 ----------------
__global__ __launch_bounds__(256) void k_red8(const float* __restrict__ part,
                                              float* __restrict__ dbl,
                                              unsigned short* __restrict__ dtr) {
    int idx = blockIdx.x * 256 + threadIdx.x;   // 2048*128
    float s = 0.f;
    #pragma unroll
    for (int z = 0; z < 8; ++z) s += part[(size_t)z * 262144 + idx];
    dbl[idx] = s;
    int r = idx >> 7, c = idx & 127;
    if (c < 64) dtr[r * 64 + c] = f2bf(s);
}

// ---------------- causal depthwise conv (width 4, bf16 in) + SiLU -> bf16 ------
__global__ __launch_bounds__(256) void k_conv2(const unsigned short* __restrict__ UB,
                                               const float* __restrict__ cw,
                                               const float* __restrict__ cb,
                                               unsigned short* __restrict__ ucb) {
    int idx = blockIdx.x * 256 + threadIdx.x;   // (b*L+l)*2048 + e
    int e  = idx & 2047;
    int bl = idx >> 11;
    int l  = bl & 1023;
    float acc = cb[e];
    float4 wv = *(const float4*)(cw + e * 4);
    float w4[4] = {wv.x, wv.y, wv.z, wv.w};
    #pragma unroll
    for (int k = 0; k < 4; ++k) {
        int ls = l - 3 + k;
        if (ls >= 0) acc += w4[k] * bf2f(UB[(size_t)(bl - 3 + k) * 2048 + e]);
    }
    ucb[idx] = f2bf(silu(acc));
}

// ---------------- chunked scan, lane-owns-element, 32 chunks of 32 ------------
// DTB/UCB/SZ/YG bf16, layout [b*1024+l][2048]. DBL [.][128], B@64 C@80.
// AGGH/HINIT: ((b*32+c)*16+n)*2048+e (8MB each). SDT: (b*32+c)*2048+e (512KB).

__global__ __launch_bounds__(256) void k_scan_p1(const unsigned short* __restrict__ ucb,
                                                 const unsigned short* __restrict__ dtb,
                                                 const float* __restrict__ dbl,
                                                 const float* __restrict__ A_log,
                                                 float* __restrict__ aggH,
                                                 float* __restrict__ sdtb) {
    __shared__ float sB[32][16];
    int bid = blockIdx.x;                       // 512 = 2b * 8eblk * 32c
    int c = bid & 31, eblk = (bid >> 5) & 7, b = bid >> 8;
    int t = threadIdx.x;
    int e = eblk * 256 + t;
    int bl0 = b * 1024 + c * 32;
    if (t < 128) {
        int r = t >> 2, j4 = t & 3;
        *(float4*)&sB[r][j4 * 4] = *(const float4*)(dbl + (size_t)(bl0 + r) * 128 + 64 + j4 * 4);
    }
    __syncthreads();
    float Aen[16];
    #pragma unroll
    for (int n = 0; n < 16; ++n) Aen[n] = -__expf(A_log[e * 16 + n]);
    bool fastA = true;
    #pragma unroll
    for (int n = 1; n < 16; ++n)
        fastA = fastA && (fabsf(Aen[n] - (n + 1) * Aen[0]) <= 1e-3f);
    float h[16];
    #pragma unroll
    for (int n = 0; n < 16; ++n) h[n] = 0.f;
    float sdt = 0.f;
    size_t iu = (size_t)bl0 * 2048 + e;
    #pragma unroll 4
    for (int l = 0; l < 32; ++l) {
        float dtv = bf2f(dtb[iu]);
        float ucv = bf2f(ucb[iu]);
        float dtu = dtv * ucv;
        float dA[16];
        if (fastA) powers16(__expf(dtv * Aen[0]), dA);
        else {
            #pragma unroll
            for (int n = 0; n < 16; ++n) dA[n] = __expf(dtv * Aen[n]);
        }
        #pragma unroll
        for (int n = 0; n < 16; ++n)
            h[n] = fmaf(dA[n], h[n], dtu * sB[l][n]);
        sdt += dtv;
        iu += 2048;
    }
    size_t o = ((size_t)(b * 32 + c) * 16) * 2048 + e;
    #pragma unroll
    for (int n = 0; n < 16; ++n) aggH[o + (size_t)n * 2048] = h[n];
    sdtb[(size_t)(b * 32 + c) * 2048 + e] = sdt;
}

// Pass 2: scan 32 chunk aggregates -> initial h per chunk (balanced p3).
__global__ __launch_bounds__(256) void k_scan_p2(const float* __restrict__ aggH,
                                                 const float* __restrict__ sdtb,
                                                 const float* __restrict__ A_log,
                                                 float* __restrict__ hinit) {
    int idx = blockIdx.x * 256 + threadIdx.x;   // 65536 = 2b * 16n * 2048e
    int b = idx >> 15;
    int n = (idx >> 11) & 15;
    int e = idx & 2047;
    float Aen = -__expf(A_log[e * 16 + n]);
    float h = 0.f;
    #pragma unroll 4
    for (int c = 0; c < 32; ++c) {
        size_t base = ((size_t)(b * 32 + c) * 16 + n) * 2048 + e;
        hinit[base] = h;
        float a = __expf(sdtb[(size_t)(b * 32 + c) * 2048 + e] * Aen);
        h = fmaf(a, h, aggH[base]);
    }
}

__global__ __launch_bounds__(256) void k_scan_p3(const unsigned short* __restrict__ ucb,
                                                 const unsigned short* __restrict__ dtb,
                                                 const float* __restrict__ dbl,
                                                 const unsigned short* __restrict__ sz,
                                                 const float* __restrict__ A_log,
                                                 const float* __restrict__ D_skip,
                                                 const float* __restrict__ hinit,
                                                 unsigned short* __restrict__ yg) {
    __shared__ float sBC[32][32];
    int bid = blockIdx.x;                       // 512
    int c = bid & 31, eblk = (bid >> 5) & 7, b = bid >> 8;
    int t = threadIdx.x;
    int e = eblk * 256 + t;
    int bl0 = b * 1024 + c * 32;
    {
        int r = t >> 3, j = t & 7;
        *(float4*)&sBC[r][j * 4] = *(const float4*)(dbl + (size_t)(bl0 + r) * 128 + 64 + j * 4);
    }
    __syncthreads();
    float Aen[16];
    #pragma unroll
    for (int n = 0; n < 16; ++n) Aen[n] = -__expf(A_log[e * 16 + n]);
    bool fastA = true;
    #pragma unroll
    for (int n = 1; n < 16; ++n)
        fastA = fastA && (fabsf(Aen[n] - (n + 1) * Aen[0]) <= 1e-3f);
    float De = D_skip[e];
    size_t o = ((size_t)(b * 32 + c) * 16) * 2048 + e;
    float h[16];
    #pragma unroll
    for (int n = 0; n < 16; ++n) h[n] = hinit[o + (size_t)n * 2048];
    size_t iu = (size_t)bl0 * 2048 + e;
    #pragma unroll 4
    for (int l = 0; l < 32; ++l) {
        float dtv = bf2f(dtb[iu]);
        float ucv = bf2f(ucb[iu]);
        float szv = bf2f(sz[iu]);
        float dtu = dtv * ucv;
        float dA[16];
        if (fastA) powers16(__expf(dtv * Aen[0]), dA);
        else {
            #pragma unroll
            for (int n = 0; n < 16; ++n) dA[n] = __expf(dtv * Aen[n]);
        }
        float y0 = 0.f, y1 = 0.f, y2 = 0.f, y3 = 0.f;
        #pragma unroll
        for (int n = 0; n < 16; n += 4) {
            h[n]     = fmaf(dA[n],     h[n],     dtu * sBC[l][n]);
            h[n + 1] = fmaf(dA[n + 1], h[n + 1], dtu * sBC[l][n + 1]);
            h[n + 2] = fmaf(dA[n + 2], h[n + 2], dtu * sBC[l][n + 2]);
            h[n + 3] = fmaf(dA[n + 3], h[n + 3], dtu * sBC[l][n + 3]);
            y0 = fmaf(h[n],     sBC[l][16 + n],     y0);
            y1 = fmaf(h[n + 1], sBC[l][16 + n + 1], y1);
            y2 = fmaf(h[n + 2], sBC[l][16 + n + 2], y2);
            y3 = fmaf(h[n + 3], sBC[l][16 + n + 3], y3);
        }
        float y = (y0 + y1) + (y2 + y3);
        y = (y + ucv * De) * szv;
        yg[iu] = f2bf(y);
        iu += 2048;
    }
}

// ---------------- launch ----------------
extern "C" void kernel_launch(void* const* d_in, const int* in_sizes, int n_in,
                              void* d_out, int out_size, void* d_ws, size_t ws_size,
                              hipStream_t stream) {
    const float* x      = (const float*)d_in[0];
    const float* ln_g   = (const float*)d_in[1];
    const float* ln_b   = (const float*)d_in[2];
    const float* W_in   = (const float*)d_in[3];
    const float* conv_w = (const float*)d_in[4];
    const float* conv_b = (const float*)d_in[5];
    const float* W_x    = (const float*)d_in[6];
    const float* W_dt   = (const float*)d_in[7];
    const float* b_dt   = (const float*)d_in[8];
    const float* A_log  = (const float*)d_in[9];
    const float* D_skip = (const float*)d_in[10];
    const float* W_out  = (const float*)d_in[11];
    float* out = (float*)d_out;

    const size_t needed =
        (size_t)4096 * 1024 * 2 + (size_t)1024 * 2048 * 2 + (size_t)2048 * 64 * 2 +
        (size_t)128 * 2048 * 2 + (size_t)2048 * 1024 * 2 + (size_t)2048 * 4096 * 4 +
        (size_t)2048 * 2048 * 4 + (size_t)2048 * 2048 * 2 + (size_t)2048 * 128 * 4 +
        (size_t)2048 * 64 * 2 + (size_t)2048 * 2048 * 4 + (size_t)2048 * 2048 * 2;
    if (ws_size < needed) return;

    char* w = (char*)d_ws;
    unsigned short* WIN_T  = (unsigned short*)w; w += (size_t)4096 * 1024 * 2;   // 8 MB
    unsigned short* WOUT_T = (unsigned short*)w; w += (size_t)1024 * 2048 * 2;   // 4 MB
    unsigned short* WDT_T  = (unsigned short*)w; w += (size_t)2048 * 64 * 2;
    unsigned short* WX_T   = (unsigned short*)w; w += (size_t)128 * 2048 * 2;
    unsigned short* XN     = (unsigned short*)w; w += (size_t)2048 * 1024 * 2;   // 4 MB
    unsigned short* UB     = (unsigned short*)w; w += (size_t)2048 * 2048 * 2;   // 8 MB
    unsigned short* SZ     = (unsigned short*)w; w += (size_t)2048 * 2048 * 2;   // 8 MB
    unsigned short* UCB    = (unsigned short*)w; w += (size_t)2048 * 2048 * 2;   // 8 MB
    float*          DBL    = (float*)w;          w += (size_t)2048 * 128 * 4;    // 1 MB
    unsigned short* DTR    = (unsigned short*)w; w += (size_t)2048 * 64 * 2;
    unsigned short* DTB    = (unsigned short*)w; w += (size_t)2048 * 2048 * 4;   // bf16 dt (uses 8 of 16 MB)
    unsigned short* YG     = (unsigned short*)w; w += (size_t)2048 * 2048 * 2;   // 8 MB

    // aliases on dead regions:
    // PART (8MB) on WIN_T (dead after GEMM1; PART dead after red8)
    // AGGH (8MB) on WIN_T ; SDT (512KB) on XN ; HINIT (8MB) on UB (dead after conv2)
    float* PART  = (float*)WIN_T;
    float* AGGH  = (float*)WIN_T;
    float* SDT   = (float*)XN;
    float* HINIT = (float*)UB;

    // 1. prep: LN + all weight transposes
    k_prep<<<8576, 256, 0, stream>>>(x, ln_g, ln_b, XN,
                                     W_in, WIN_T, W_out, WOUT_T, W_dt, WDT_T, W_x, WX_T);

    // 2. u,z = xn @ W_in ; u -> UB bf16, z -> SZ = silu(z) bf16
    k_gemm2<128, 128, 2><<<dim3(16, 32, 1), 256, 0, stream>>>(XN, WIN_T, nullptr, UB, SZ, 1024, 1024, 1024, 2048, 0, nullptr);

    // 3. uc(bf16) = silu(conv(u))
    k_conv2<<<16384, 256, 0, stream>>>(UB, conv_w, conv_b, UCB);

    // 4. dbl partials = uc @ W_x (split-K x8)
    k_gemm2<64, 128, 0><<<dim3(32, 1, 8), 256, 0, stream>>>(UCB, WX_T, PART, nullptr, nullptr, 256, 2048, 2048, 128, (size_t)2048 * 128, nullptr);

    // 5. reduce partials -> DBL fp32 + DTR bf16
    k_red8<<<1024, 256, 0, stream>>>(PART, DBL, DTR);

    // 6. dt = softplus(dtr @ W_dt + b_dt) -> bf16 DTB
    k_gemm2<128, 128, 3><<<dim3(16, 16, 1), 256, 0, stream>>>(DTR, WDT_T, nullptr, DTB, nullptr, 64, 64, 64, 2048, 0, b_dt);

    // 7/8/9. chunked scan (32 chunks of 32; separate balanced p2)
    k_scan_p1<<<512, 256, 0, stream>>>(UCB, DTB, DBL, A_log, AGGH, SDT);
    k_scan_p2<<<256, 256, 0, stream>>>(AGGH, SDT, A_log, HINIT);
    k_scan_p3<<<512, 256, 0, stream>>>(UCB, DTB, DBL, SZ, A_log, D_skip, HINIT, YG);

    // 10. out = yg @ W_out
    k_gemm2<64, 128, 0><<<dim3(32, 8, 1), 256, 0, stream>>>(YG, WOUT_T, out, nullptr, nullptr, 2048, 2048, 2048, 1024, 0, nullptr);
}

// Round 13
// 235.905 us; speedup vs baseline: 1.9845x; 1.4913x over previous
//
#include <hip/hip_runtime.h>
#include <hip/hip_bf16.h>

// ---------------- types & helpers ----------------
typedef __attribute__((ext_vector_type(4))) float  f32x4;
typedef __attribute__((ext_vector_type(8))) __bf16 bf16x8;
typedef __attribute__((ext_vector_type(8))) unsigned short u16x8;

typedef __attribute__((address_space(1))) void gvoid_t;
typedef __attribute__((address_space(3))) void lvoid_t;

__device__ __forceinline__ void gld16(const void* g, void* l) {
    __builtin_amdgcn_global_load_lds((const gvoid_t*)g, (lvoid_t*)l, 16, 0, 0);
}

template <int N> __device__ __forceinline__ void vwait() {
    if constexpr (N == 0)      asm volatile("s_waitcnt vmcnt(0)" ::: "memory");
    else if constexpr (N == 6) asm volatile("s_waitcnt vmcnt(6)" ::: "memory");
    else if constexpr (N == 8) asm volatile("s_waitcnt vmcnt(8)" ::: "memory");
}

__device__ __forceinline__ unsigned short f2bf(float f) {
    unsigned u = __builtin_bit_cast(unsigned, f);
    u += 0x7fffu + ((u >> 16) & 1u);
    return (unsigned short)(u >> 16);
}
__device__ __forceinline__ float bf2f(unsigned short u) {
    return __builtin_bit_cast(float, (unsigned)u << 16);
}
__device__ __forceinline__ float silu(float x) {
    return x / (1.f + __expf(-x));
}

// log-depth powers: dA[n] = p^(n+1), n=0..15 (depth ~5)
__device__ __forceinline__ void powers16(float p, float* dA) {
    float p2 = p * p, p4 = p2 * p2, p8 = p4 * p4, p16 = p8 * p8;
    float q[5] = {p, p2, p4, p8, p16};
    #pragma unroll
    for (int n = 0; n < 16; ++n) {
        int m = n + 1;
        float r = 1.f;
        bool first = true;
        #pragma unroll
        for (int bit = 0; bit < 5; ++bit) {
            if (m & (1 << bit)) {
                r = first ? q[bit] : r * q[bit];
                first = false;
            }
        }
        dA[n] = r;
    }
}

// ---------------- fused prep: LayerNorm + 4 weight transposes ----------------
__device__ __forceinline__ void tr_cvt(const float* __restrict__ in,
                                       unsigned short* __restrict__ out,
                                       int K, int N, int Npad, int bnb, int bkb,
                                       float* sh) {
    float (*t)[33] = (float(*)[33])sh;
    int bn = bnb * 32, bk = bkb * 32;
    int c = threadIdx.x & 31, r0 = threadIdx.x >> 5;
    #pragma unroll
    for (int rr = r0; rr < 32; rr += 8) {
        int k = bk + rr, n = bn + c;
        t[rr][c] = (k < K && n < N) ? in[(size_t)k * N + n] : 0.f;
    }
    __syncthreads();
    #pragma unroll
    for (int rr = r0; rr < 32; rr += 8) {
        int n = bn + rr, k = bk + c;
        if (n < Npad && k < K) out[(size_t)n * K + k] = f2bf(t[c][rr]);
    }
}

__global__ __launch_bounds__(256) void k_prep(const float* __restrict__ x,
                                              const float* __restrict__ g,
                                              const float* __restrict__ b,
                                              unsigned short* __restrict__ xn,
                                              const float* __restrict__ W_in,  unsigned short* __restrict__ WIN_T,
                                              const float* __restrict__ W_out, unsigned short* __restrict__ WOUT_T,
                                              const float* __restrict__ W_dt,  unsigned short* __restrict__ WDT_T,
                                              const float* __restrict__ W_x,   unsigned short* __restrict__ WX_T) {
    __shared__ float sh[32 * 33];
    int bid = blockIdx.x;
    if (bid < 2048) {
        int row = bid;
        const float4* xr = (const float4*)(x + (size_t)row * 1024);
        float4 v = xr[threadIdx.x];
        float s  = v.x + v.y + v.z + v.w;
        float ss = v.x*v.x + v.y*v.y + v.z*v.z + v.w*v.w;
        #pragma unroll
        for (int o = 32; o > 0; o >>= 1) { s += __shfl_down(s, o); ss += __shfl_down(ss, o); }
        if ((threadIdx.x & 63) == 0) { sh[threadIdx.x >> 6] = s; sh[4 + (threadIdx.x >> 6)] = ss; }
        __syncthreads();
        s  = sh[0] + sh[1] + sh[2] + sh[3];
        ss = sh[4] + sh[5] + sh[6] + sh[7];
        float mu  = s * (1.f / 1024.f);
        float inv = rsqrtf(ss * (1.f / 1024.f) - mu * mu + 1e-5f);
        float4 gv = ((const float4*)g)[threadIdx.x];
        float4 bv = ((const float4*)b)[threadIdx.x];
        ushort4 o4;
        o4.x = f2bf((v.x - mu) * inv * gv.x + bv.x);
        o4.y = f2bf((v.y - mu) * inv * gv.y + bv.y);
        o4.z = f2bf((v.z - mu) * inv * gv.z + bv.z);
        o4.w = f2bf((v.w - mu) * inv * gv.w + bv.w);
        ((ushort4*)xn)[(size_t)row * 256 + threadIdx.x] = o4;
    } else if (bid < 6144) {
        int i = bid - 2048;  tr_cvt(W_in,  WIN_T,  1024, 4096, 4096, i & 127, i >> 7, sh);
    } else if (bid < 8192) {
        int i = bid - 6144;  tr_cvt(W_out, WOUT_T, 2048, 1024, 1024, i & 31,  i >> 5, sh);
    } else if (bid < 8320) {
        int i = bid - 8192;  tr_cvt(W_dt,  WDT_T,  64,   2048, 2048, i & 63,  i >> 6, sh);
    } else {
        int i = bid - 8320;  tr_cvt(W_x,   WX_T,   2048, 96,   128,  i & 3,   i >> 2, sh);
    }
}

// ---------------- pipelined bf16 MFMA GEMM (2-phase, BK=64, XOR-swizzled LDS) ----
// LDS-transposed coalesced epilogue (256-B bursts).
// EPI: 0 = fp32 -> C (BM must be 64: fp32 tile fits LDS)
//      2 = bn<2048 ? bf16 -> C2 : bf16(silu) -> C3   (ld 2048, block-uniform side)
//      3 = softplus(x+bias[col]) -> bf16 -> C2
template <int BM, int BN, int EPI>
__global__ __launch_bounds__(256) void k_gemm2(const unsigned short* __restrict__ A,
                                               const unsigned short* __restrict__ Bt,
                                               float* __restrict__ C,
                                               unsigned short* __restrict__ C2,
                                               unsigned short* __restrict__ C3,
                                               int kchunk, int lda, int ldb, int ldc,
                                               size_t zstride,
                                               const float* __restrict__ bias) {
    constexpr int PA = BM / 32, PB = BN / 32, NV = PA + PB;
    constexpr int MF = BM / 32, NF = BN / 32;
    __shared__ __attribute__((aligned(16))) unsigned short sm[2 * BM * 64 + 2 * BN * 64];
    unsigned short* smA = sm;
    unsigned short* smB = sm + 2 * BM * 64;

    int tid = threadIdx.x, wave = tid >> 6, lane = tid & 63;
    int bm = blockIdx.x * BM, bn = blockIdx.y * BN;
    int kstart = blockIdx.z * kchunk;
    int nt = kchunk >> 6;
    C += (size_t)blockIdx.z * zstride;
    int wm = (wave >> 1) * (BM / 2), wn = (wave & 1) * (BN / 2);
    int lr = lane & 15, lq = lane >> 4;
    int srow = wave * 8 + (lane >> 3);
    int scg  = lane & 7;

    f32x4 acc[MF][NF] = {};

    auto STAGE = [&](int buf, int k0) {
        unsigned short* dA = smA + buf * (BM * 64) + wave * 512;
        unsigned short* dB = smB + buf * (BN * 64) + wave * 512;
        #pragma unroll
        for (int p = 0; p < PA; ++p) {
            int row = p * 32 + srow;
            int gcol = ((scg ^ (row & 7)) << 3) + k0;
            gld16(A + (size_t)(bm + row) * lda + gcol, dA + p * 2048);
        }
        #pragma unroll
        for (int p = 0; p < PB; ++p) {
            int row = p * 32 + srow;
            int gcol = ((scg ^ (row & 7)) << 3) + k0;
            gld16(Bt + (size_t)(bn + row) * ldb + gcol, dB + p * 2048);
        }
    };

    STAGE(0, kstart);
    for (int t = 0; t < nt; ++t) {
        int cur = t & 1;
        if (t + 1 < nt) { STAGE(cur ^ 1, kstart + (t + 1) * 64); vwait<NV>(); }
        else            { vwait<0>(); }
        __builtin_amdgcn_s_barrier();
        const unsigned short* sA = smA + cur * (BM * 64);
        const unsigned short* sB = smB + cur * (BN * 64);
        #pragma unroll
        for (int ks = 0; ks < 2; ++ks) {
            int cg = (ks * 4 + lq) ^ (lr & 7);
            bf16x8 af[MF], bfv[NF];
            #pragma unroll
            for (int i = 0; i < MF; ++i)
                af[i] = *(const bf16x8*)(sA + (wm + i * 16 + lr) * 64 + (cg << 3));
            #pragma unroll
            for (int i = 0; i < NF; ++i)
                bfv[i] = *(const bf16x8*)(sB + (wn + i * 16 + lr) * 64 + (cg << 3));
            #pragma unroll
            for (int mi = 0; mi < MF; ++mi)
                #pragma unroll
                for (int ni = 0; ni < NF; ++ni)
                    acc[mi][ni] = __builtin_amdgcn_mfma_f32_16x16x32_bf16(af[mi], bfv[ni], acc[mi][ni], 0, 0, 0);
        }
        __builtin_amdgcn_s_barrier();
    }

    // ---- LDS-transposed epilogue: 256-B global bursts ----
    if (EPI == 0) {
        // fp32 tile [BM][BN+4] (row 16B-aligned, 4-bank skew); fits for BM=64
        constexpr int PADF = BN + 4;
        float* ftile = (float*)sm;
        #pragma unroll
        for (int mi = 0; mi < MF; ++mi)
            #pragma unroll
            for (int ni = 0; ni < NF; ++ni)
                #pragma unroll
                for (int v = 0; v < 4; ++v)
                    ftile[(wm + mi * 16 + (lq << 2) + v) * PADF + wn + ni * 16 + lr] = acc[mi][ni][v];
        __syncthreads();
        #pragma unroll
        for (int q = tid; q < BM * BN / 4; q += 256) {
            int row = q / (BN / 4);
            int cc  = (q % (BN / 4)) * 4;
            float4 vv = *(const float4*)(ftile + row * PADF + cc);
            *(float4*)(C + (size_t)(bm + row) * ldc + bn + cc) = vv;
        }
    } else {
        // bf16 tile [BM][BN+8]
        constexpr int PADH = BN + 8;
        unsigned short* stile = sm;
        unsigned short* dst;
        int bnn;
        if (EPI == 3) { dst = C2; bnn = bn; }
        else          { dst = (bn < 2048) ? C2 : C3; bnn = bn & 2047; }
        #pragma unroll
        for (int mi = 0; mi < MF; ++mi) {
            #pragma unroll
            for (int ni = 0; ni < NF; ++ni) {
                int c = bn + wn + ni * 16 + lr;
                #pragma unroll
                for (int v = 0; v < 4; ++v) {
                    float val = acc[mi][ni][v];
                    if (EPI == 3) {
                        val += bias[c];
                        val = (val > 20.f) ? val : log1pf(__expf(val));
                    } else if (bn >= 2048) {
                        val = silu(val);
                    }
                    stile[(wm + mi * 16 + (lq << 2) + v) * PADH + wn + ni * 16 + lr] = f2bf(val);
                }
            }
        }
        __syncthreads();
        #pragma unroll
        for (int q = tid; q < BM * BN / 8; q += 256) {
            int row = q / (BN / 8);
            int cc  = (q % (BN / 8)) * 8;
            u16x8 vv = *(const u16x8*)(stile + row * PADH + cc);
            *(u16x8*)(dst + (size_t)(bm + row) * ldc + bnn + cc) = vv;
        }
    }
}

// ---------------- split-K reduce (8 partials) + dtr bf16 ----------------
__global__ __launch_bounds__(256) void k_red8(const float* __restrict__ part,
                                              float* __restrict__ dbl,
                                              unsigned short* __restrict__ dtr) {
    int idx = blockIdx.x * 256 + threadIdx.x;   // 2048*128
    float s = 0.f;
    #pragma unroll
    for (int z = 0; z < 8; ++z) s += part[(size_t)z * 262144 + idx];
    dbl[idx] = s;
    int r = idx >> 7, c = idx & 127;
    if (c < 64) dtr[r * 64 + c] = f2bf(s);
}

// ---------------- causal depthwise conv (width 4, bf16 in) + SiLU -> bf16 ------
__global__ __launch_bounds__(256) void k_conv2(const unsigned short* __restrict__ UB,
                                               const float* __restrict__ cw,
                                               const float* __restrict__ cb,
                                               unsigned short* __restrict__ ucb) {
    int idx = blockIdx.x * 256 + threadIdx.x;   // (b*L+l)*2048 + e
    int e  = idx & 2047;
    int bl = idx >> 11;
    int l  = bl & 1023;
    float acc = cb[e];
    float4 wv = *(const float4*)(cw + e * 4);
    float w4[4] = {wv.x, wv.y, wv.z, wv.w};
    #pragma unroll
    for (int k = 0; k < 4; ++k) {
        int ls = l - 3 + k;
        if (ls >= 0) acc += w4[k] * bf2f(UB[(size_t)(bl - 3 + k) * 2048 + e]);
    }
    ucb[idx] = f2bf(silu(acc));
}

// ---------------- chunked scan, lane-owns-element, 32 chunks of 32 ------------
// DTB/UCB/SZ/YG bf16, layout [b*1024+l][2048]. DBL [.][128], B@64 C@80.
// AGGH/HINIT: ((b*32+c)*16+n)*2048+e (8MB each). SDT: (b*32+c)*2048+e (512KB).

__global__ __launch_bounds__(256) void k_scan_p1(const unsigned short* __restrict__ ucb,
                                                 const unsigned short* __restrict__ dtb,
                                                 const float* __restrict__ dbl,
                                                 const float* __restrict__ A_log,
                                                 float* __restrict__ aggH,
                                                 float* __restrict__ sdtb) {
    __shared__ float sB[32][16];
    int bid = blockIdx.x;                       // 512 = 2b * 8eblk * 32c
    int c = bid & 31, eblk = (bid >> 5) & 7, b = bid >> 8;
    int t = threadIdx.x;
    int e = eblk * 256 + t;
    int bl0 = b * 1024 + c * 32;
    if (t < 128) {
        int r = t >> 2, j4 = t & 3;
        *(float4*)&sB[r][j4 * 4] = *(const float4*)(dbl + (size_t)(bl0 + r) * 128 + 64 + j4 * 4);
    }
    __syncthreads();
    float Aen[16];
    #pragma unroll
    for (int n = 0; n < 16; ++n) Aen[n] = -__expf(A_log[e * 16 + n]);
    bool fastA = true;
    #pragma unroll
    for (int n = 1; n < 16; ++n)
        fastA = fastA && (fabsf(Aen[n] - (n + 1) * Aen[0]) <= 1e-3f);
    float h[16];
    #pragma unroll
    for (int n = 0; n < 16; ++n) h[n] = 0.f;
    float sdt = 0.f;
    size_t iu = (size_t)bl0 * 2048 + e;
    #pragma unroll 4
    for (int l = 0; l < 32; ++l) {
        float dtv = bf2f(dtb[iu]);
        float ucv = bf2f(ucb[iu]);
        float dtu = dtv * ucv;
        float dA[16];
        if (fastA) powers16(__expf(dtv * Aen[0]), dA);
        else {
            #pragma unroll
            for (int n = 0; n < 16; ++n) dA[n] = __expf(dtv * Aen[n]);
        }
        #pragma unroll
        for (int n = 0; n < 16; ++n)
            h[n] = fmaf(dA[n], h[n], dtu * sB[l][n]);
        sdt += dtv;
        iu += 2048;
    }
    size_t o = ((size_t)(b * 32 + c) * 16) * 2048 + e;
    #pragma unroll
    for (int n = 0; n < 16; ++n) aggH[o + (size_t)n * 2048] = h[n];
    sdtb[(size_t)(b * 32 + c) * 2048 + e] = sdt;
}

// Pass 2: scan 32 chunk aggregates -> initial h per chunk (balanced p3).
__global__ __launch_bounds__(256) void k_scan_p2(const float* __restrict__ aggH,
                                                 const float* __restrict__ sdtb,
                                                 const float* __restrict__ A_log,
                                                 float* __restrict__ hinit) {
    int idx = blockIdx.x * 256 + threadIdx.x;   // 65536 = 2b * 16n * 2048e
    int b = idx >> 15;
    int n = (idx >> 11) & 15;
    int e = idx & 2047;
    float Aen = -__expf(A_log[e * 16 + n]);
    float h = 0.f;
    #pragma unroll 4
    for (int c = 0; c < 32; ++c) {
        size_t base = ((size_t)(b * 32 + c) * 16 + n) * 2048 + e;
        hinit[base] = h;
        float a = __expf(sdtb[(size_t)(b * 32 + c) * 2048 + e] * Aen);
        h = fmaf(a, h, aggH[base]);
    }
}

__global__ __launch_bounds__(256) void k_scan_p3(const unsigned short* __restrict__ ucb,
                                                 const unsigned short* __restrict__ dtb,
                                                 const float* __restrict__ dbl,
                                                 const unsigned short* __restrict__ sz,
                                                 const float* __restrict__ A_log,
                                                 const float* __restrict__ D_skip,
                                                 const float* __restrict__ hinit,
                                                 unsigned short* __restrict__ yg) {
    __shared__ float sBC[32][32];
    int bid = blockIdx.x;                       // 512
    int c = bid & 31, eblk = (bid >> 5) & 7, b = bid >> 8;
    int t = threadIdx.x;
    int e = eblk * 256 + t;
    int bl0 = b * 1024 + c * 32;
    {
        int r = t >> 3, j = t & 7;
        *(float4*)&sBC[r][j * 4] = *(const float4*)(dbl + (size_t)(bl0 + r) * 128 + 64 + j * 4);
    }
    __syncthreads();
    float Aen[16];
    #pragma unroll
    for (int n = 0; n < 16; ++n) Aen[n] = -__expf(A_log[e * 16 + n]);
    bool fastA = true;
    #pragma unroll
    for (int n = 1; n < 16; ++n)
        fastA = fastA && (fabsf(Aen[n] - (n + 1) * Aen[0]) <= 1e-3f);
    float De = D_skip[e];
    size_t o = ((size_t)(b * 32 + c) * 16) * 2048 + e;
    float h[16];
    #pragma unroll
    for (int n = 0; n < 16; ++n) h[n] = hinit[o + (size_t)n * 2048];
    size_t iu = (size_t)bl0 * 2048 + e;
    #pragma unroll 4
    for (int l = 0; l < 32; ++l) {
        float dtv = bf2f(dtb[iu]);
        float ucv = bf2f(ucb[iu]);
        float szv = bf2f(sz[iu]);
        float dtu = dtv * ucv;
        float dA[16];
        if (fastA) powers16(__expf(dtv * Aen[0]), dA);
        else {
            #pragma unroll
            for (int n = 0; n < 16; ++n) dA[n] = __expf(dtv * Aen[n]);
        }
        float y0 = 0.f, y1 = 0.f, y2 = 0.f, y3 = 0.f;
        #pragma unroll
        for (int n = 0; n < 16; n += 4) {
            h[n]     = fmaf(dA[n],     h[n],     dtu * sBC[l][n]);
            h[n + 1] = fmaf(dA[n + 1], h[n + 1], dtu * sBC[l][n + 1]);
            h[n + 2] = fmaf(dA[n + 2], h[n + 2], dtu * sBC[l][n + 2]);
            h[n + 3] = fmaf(dA[n + 3], h[n + 3], dtu * sBC[l][n + 3]);
            y0 = fmaf(h[n],     sBC[l][16 + n],     y0);
            y1 = fmaf(h[n + 1], sBC[l][16 + n + 1], y1);
            y2 = fmaf(h[n + 2], sBC[l][16 + n + 2], y2);
            y3 = fmaf(h[n + 3], sBC[l][16 + n + 3], y3);
        }
        float y = (y0 + y1) + (y2 + y3);
        y = (y + ucv * De) * szv;
        yg[iu] = f2bf(y);
        iu += 2048;
    }
}

// ---------------- launch ----------------
extern "C" void kernel_launch(void* const* d_in, const int* in_sizes, int n_in,
                              void* d_out, int out_size, void* d_ws, size_t ws_size,
                              hipStream_t stream) {
    const float* x      = (const float*)d_in[0];
    const float* ln_g   = (const float*)d_in[1];
    const float* ln_b   = (const float*)d_in[2];
    const float* W_in   = (const float*)d_in[3];
    const float* conv_w = (const float*)d_in[4];
    const float* conv_b = (const float*)d_in[5];
    const float* W_x    = (const float*)d_in[6];
    const float* W_dt   = (const float*)d_in[7];
    const float* b_dt   = (const float*)d_in[8];
    const float* A_log  = (const float*)d_in[9];
    const float* D_skip = (const float*)d_in[10];
    const float* W_out  = (const float*)d_in[11];
    float* out = (float*)d_out;

    const size_t needed =
        (size_t)4096 * 1024 * 2 + (size_t)1024 * 2048 * 2 + (size_t)2048 * 64 * 2 +
        (size_t)128 * 2048 * 2 + (size_t)2048 * 1024 * 2 + (size_t)2048 * 4096 * 4 +
        (size_t)2048 * 2048 * 4 + (size_t)2048 * 2048 * 2 + (size_t)2048 * 128 * 4 +
        (size_t)2048 * 64 * 2 + (size_t)2048 * 2048 * 4 + (size_t)2048 * 2048 * 2;
    if (ws_size < needed) return;

    char* w = (char*)d_ws;
    unsigned short* WIN_T  = (unsigned short*)w; w += (size_t)4096 * 1024 * 2;   // 8 MB
    unsigned short* WOUT_T = (unsigned short*)w; w += (size_t)1024 * 2048 * 2;   // 4 MB
    unsigned short* WDT_T  = (unsigned short*)w; w += (size_t)2048 * 64 * 2;
    unsigned short* WX_T   = (unsigned short*)w; w += (size_t)128 * 2048 * 2;
    unsigned short* XN     = (unsigned short*)w; w += (size_t)2048 * 1024 * 2;   // 4 MB
    unsigned short* UB     = (unsigned short*)w; w += (size_t)2048 * 2048 * 2;   // 8 MB
    unsigned short* SZ     = (unsigned short*)w; w += (size_t)2048 * 2048 * 2;   // 8 MB
    unsigned short* UCB    = (unsigned short*)w; w += (size_t)2048 * 2048 * 2;   // 8 MB
    float*          DBL    = (float*)w;          w += (size_t)2048 * 128 * 4;    // 1 MB
    unsigned short* DTR    = (unsigned short*)w; w += (size_t)2048 * 64 * 2;
    unsigned short* DTB    = (unsigned short*)w; w += (size_t)2048 * 2048 * 4;   // bf16 dt (8 of 16 MB)
    unsigned short* YG     = (unsigned short*)w; w += (size_t)2048 * 2048 * 2;   // 8 MB

    // aliases on dead regions:
    // PART (8MB) on WIN_T (dead after GEMM1; PART dead after red8)
    // AGGH (8MB) on WIN_T ; SDT (512KB) on XN ; HINIT (8MB) on UB (dead after conv2)
    float* PART  = (float*)WIN_T;
    float* AGGH  = (float*)WIN_T;
    float* SDT   = (float*)XN;
    float* HINIT = (float*)UB;

    // 1. prep: LN + all weight transposes
    k_prep<<<8576, 256, 0, stream>>>(x, ln_g, ln_b, XN,
                                     W_in, WIN_T, W_out, WOUT_T, W_dt, WDT_T, W_x, WX_T);

    // 2. u,z = xn @ W_in ; u -> UB bf16, z -> SZ = silu(z) bf16
    k_gemm2<128, 128, 2><<<dim3(16, 32, 1), 256, 0, stream>>>(XN, WIN_T, nullptr, UB, SZ, 1024, 1024, 1024, 2048, 0, nullptr);

    // 3. uc(bf16) = silu(conv(u))
    k_conv2<<<16384, 256, 0, stream>>>(UB, conv_w, conv_b, UCB);

    // 4. dbl partials = uc @ W_x (split-K x8)
    k_gemm2<64, 128, 0><<<dim3(32, 1, 8), 256, 0, stream>>>(UCB, WX_T, PART, nullptr, nullptr, 256, 2048, 2048, 128, (size_t)2048 * 128, nullptr);

    // 5. reduce partials -> DBL fp32 + DTR bf16
    k_red8<<<1024, 256, 0, stream>>>(PART, DBL, DTR);

    // 6. dt = softplus(dtr @ W_dt + b_dt) -> bf16 DTB
    k_gemm2<128, 128, 3><<<dim3(16, 16, 1), 256, 0, stream>>>(DTR, WDT_T, nullptr, DTB, nullptr, 64, 64, 64, 2048, 0, b_dt);

    // 7/8/9. chunked scan (32 chunks of 32; separate balanced p2)
    k_scan_p1<<<512, 256, 0, stream>>>(UCB, DTB, DBL, A_log, AGGH, SDT);
    k_scan_p2<<<256, 256, 0, stream>>>(AGGH, SDT, A_log, HINIT);
    k_scan_p3<<<512, 256, 0, stream>>>(UCB, DTB, DBL, SZ, A_log, D_skip, HINIT, YG);

    // 10. out = yg @ W_out
    k_gemm2<64, 128, 0><<<dim3(32, 8, 1), 256, 0, stream>>>(YG, WOUT_T, out, nullptr, nullptr, 2048, 2048, 2048, 1024, 0, nullptr);
}